// Round 20
// baseline (473.083 us; speedup 1.0000x reference)
//
#include <hip/hip_runtime.h>
#include <hip/hip_bf16.h>
#include <math.h>

#define B 64
#define S 2048
#define H 512
#define BS (B * S)

// workspace layout (floats)
#define QS_OFF 0                           // qs: B*H
#define SP_OFF 32768                       // score partials: 8 * B*S
#define TL_OFF 1081344                     // task list ints (<=8193), reserve 16384
#define PC_OFF 1097728                     // pc: B*NCHUNK*H (Wt aliases, used before pc)
#define E16_OFF 1622016                    // enc16: B*S*H bf16
#define OP_OFF  35176448                   // out partials: 4*B*H
#define NCHUNK 16
#define CHUNK  128                         // S / NCHUNK

typedef __attribute__((ext_vector_type(8))) short short8;
typedef __attribute__((ext_vector_type(4))) short short4v;
typedef __attribute__((ext_vector_type(4))) float f32x4;

static __device__ __forceinline__ short f2bf(float f) {
    union { float f; unsigned u; } x; x.f = f;
    unsigned r = x.u + 0x7fffu + ((x.u >> 16) & 1u);   // RNE
    return (short)(r >> 16);
}

static __device__ __forceinline__ float ftanh(float x) {
    x = fminf(fmaxf(x, -30.f), 30.f);
    const float e = __builtin_amdgcn_exp2f(x * 2.8853900817779268f); // e^(2x)
    return (e - 1.f) * __builtin_amdgcn_rcpf(e + 1.f);
}

#define GLL16(g_, l_) __builtin_amdgcn_global_load_lds(                        \
    (const __attribute__((address_space(1))) void*)(g_),                      \
    (__attribute__((address_space(3))) void*)(l_), 16, 0, 0)

// ---- fused prep: [0,1024) wt_prep | [1024,1536) cvt | [1536,1600) qs | 1600 task ----
__global__ __launch_bounds__(256) void prep_kernel(const float* __restrict__ query,
                                                   const float* __restrict__ W_s,
                                                   const float* __restrict__ W_h,
                                                   const float* __restrict__ enc,
                                                   const int* __restrict__ lens,
                                                   float* __restrict__ qs,
                                                   short* __restrict__ Wt,
                                                   short* __restrict__ enc16,
                                                   int* __restrict__ tl) {
    const int bid = blockIdx.x;
    const int t = threadIdx.x;
    if (bid < 1024) {
        const int idx = bid * 256 + t;
        const int j  = idx & 7;
        const int l  = (idx >> 3) & 63;
        const int cb = (idx >> 9) & 3;
        const int cg = (idx >> 11) & 7;
        const int st = idx >> 14;
        const int k   = st * 32 + (l >> 4) * 8 + j;
        const int col = cg * 64 + cb * 16 + (l & 15);
        Wt[idx] = f2bf(W_h[k * H + col]);
    } else if (bid < 1536) {
        const int bb = bid - 1024;
        const int b = bb >> 3, seg = bb & 7;
        const int len_r = (lens[b] + 31) & ~31;
        const int start = seg * 256;
        if (start >= len_r) return;
        const int nrows = min(256, len_r - start);
        const float4* src = (const float4*)(enc + ((size_t)b * S + start) * H);
        short4v* dst = (short4v*)(enc16 + ((size_t)b * S + start) * H);
        const int nf4 = nrows * (H / 4);
        for (int u = t; u < nf4; u += 256) {
            const float4 f = src[u];
            short4v h;
            h[0] = f2bf(f.x); h[1] = f2bf(f.y); h[2] = f2bf(f.z); h[3] = f2bf(f.w);
            dst[u] = h;
        }
    } else if (bid < 1600) {
        const int b = bid - 1536;
        __shared__ float q[H];
        q[t] = query[b * H + t];
        q[t + 256] = query[b * H + t + 256];
        __syncthreads();
        float a0 = 0.f, a1 = 0.f;
#pragma unroll 8
        for (int h = 0; h < H; ++h) {
            a0 = fmaf(q[h], W_s[h * H + t], a0);
            a1 = fmaf(q[h], W_s[h * H + t + 256], a1);
        }
        qs[b * H + t] = a0;
        qs[b * H + t + 256] = a1;
    } else {
        if (t < 64) {
            const int b = t;
            const int cnt = (lens[b] + 15) >> 4;
            int pre = cnt;
#pragma unroll
            for (int off = 1; off < 64; off <<= 1) {
                const int up = __shfl_up(pre, off);
                if (b >= off) pre += up;
            }
            if (b == 63) tl[0] = pre;
            const int start = pre - cnt;
            for (int k = 0; k < cnt; ++k) tl[1 + start + k] = (b << 16) | k;
        }
    }
}

// ------- ABLATION: scores kernel, VMASK bits: 1=stage, 2=compute, 4=epilogue -------
// Structure identical to r19 (contiguous per-wave GLL staging, 1 barrier total).
template<int VMASK>
__global__ __launch_bounds__(256) void scores_mfma_kernel(const short* __restrict__ enc16,
                                                          const short* __restrict__ Wt,
                                                          const float* __restrict__ v,
                                                          const float* __restrict__ qs,
                                                          const int* __restrict__ tl,
                                                          float* __restrict__ sp) {
    const int t = threadIdx.x;
    const int w = t >> 6, l = t & 63;
    const int g = l >> 4, c = l & 15;
    const int bid = blockIdx.x;
    const int cg = bid >> 7, jb = bid & 127;

    __shared__ __attribute__((aligned(16))) char Bs[65536];
    __shared__ __attribute__((aligned(16))) char As[4][16 * 1040];

    // one-time B load
    {
        const char* WtB = (const char*)Wt;
#pragma unroll
        for (int p = 0; p < 16; ++p) {
            const int u = p * 256 + t;
            const int st = u >> 8;
            const int off = (u & 255) << 4;
            GLL16(WtB + (size_t)((st * 8 + cg) << 12) + off, Bs + (st << 12) + off);
        }
    }
    __syncthreads();

    const int nt = tl[0];
    const int gw = jb * 4 + w;
    char* Ab = &As[w][0];

    float vreg[4];
    if constexpr (VMASK & 4) {
#pragma unroll
        for (int cb = 0; cb < 4; ++cb) vreg[cb] = v[cg * 64 + cb * 16 + c];
    }

#pragma unroll
    for (int rep = 0; rep < 16; ++rep) {
        const int i = gw + rep * 512;
        if (i < nt) {
            const int task = tl[1 + i];
            const int b0 = task >> 16;
            const int s0 = (task & 0xffff) << 4;

            if constexpr (VMASK & 1) {
                const char* aSrc = (const char*)(enc16 + ((size_t)b0 * S + s0) * H) + l * 16;
#pragma unroll
                for (int r = 0; r < 16; ++r)
                    GLL16(aSrc + r * 1024, Ab + r * 1040);
            }

            float qreg[4];
            if constexpr (VMASK & 4) {
#pragma unroll
                for (int cb = 0; cb < 4; ++cb) qreg[cb] = qs[b0 * H + cg * 64 + cb * 16 + c];
            }

            if constexpr (VMASK & 1) {
                asm volatile("s_waitcnt vmcnt(0)" ::: "memory");
                __builtin_amdgcn_sched_barrier(0);
            }

            f32x4 acc[4];
            const f32x4 z = {0.f, 0.f, 0.f, 0.f};
#pragma unroll
            for (int cb = 0; cb < 4; ++cb) acc[cb] = z;

            if constexpr (VMASK & 2) {
#pragma unroll
                for (int st = 0; st < 16; ++st) {
                    const short8 af = *(const short8*)(Ab + c * 1040 + st * 64 + g * 16);
                    const char* bb_ = Bs + (st << 12) + l * 16;
#pragma unroll
                    for (int cb = 0; cb < 4; ++cb) {
                        const short8 bf = *(const short8*)(bb_ + cb * 1024);
                        acc[cb] = __builtin_amdgcn_mfma_f32_16x16x32_bf16(af, bf, acc[cb], 0, 0, 0);
                    }
                }
            }

            if constexpr (VMASK & 4) {
                float pr[4] = {0.f, 0.f, 0.f, 0.f};
#pragma unroll
                for (int cb = 0; cb < 4; ++cb)
#pragma unroll
                    for (int r = 0; r < 4; ++r)
                        pr[r] += vreg[cb] * ftanh(acc[cb][r] + qreg[cb]);
#pragma unroll
                for (int m = 1; m < 16; m <<= 1)
#pragma unroll
                    for (int r = 0; r < 4; ++r)
                        pr[r] += __shfl_xor(pr[r], m);
                if (c == 0) {
                    float* spb = sp + (size_t)cg * BS + (size_t)b0 * S + s0;
#pragma unroll
                    for (int r = 0; r < 4; ++r)
                        spb[g * 4 + r] = pr[r];
                }
            } else {
                // rule #17: keep MFMA/staging results live without epilogue cost
#pragma unroll
                for (int cb = 0; cb < 4; ++cb)
                    asm volatile("" :: "v"(acc[cb][0]), "v"(acc[cb][1]),
                                       "v"(acc[cb][2]), "v"(acc[cb][3]));
            }
        }
    }
}

// ------ softmax over S (sums 8 col-group partials), write attn ------
__global__ __launch_bounds__(256) void softmax_kernel(const float* __restrict__ sp,
                                                      const int* __restrict__ lens,
                                                      float* __restrict__ attn) {
    const int b = blockIdx.x, t = threadIdx.x;
    const int len = lens[b];
    const int wave = t >> 6, lane = t & 63;
    __shared__ float red[4];

    float vals[8];
    float m = -INFINITY;
#pragma unroll
    for (int i = 0; i < 8; ++i) {
        const int s = i * 256 + t;
        if (s < len) {
            const size_t o = (size_t)b * S + s;
            float acc = 0.f;
#pragma unroll
            for (int p = 0; p < 8; ++p) acc += sp[(size_t)p * BS + o];
            vals[i] = acc;
        } else vals[i] = -INFINITY;
        m = fmaxf(m, vals[i]);
    }
#pragma unroll
    for (int off = 32; off > 0; off >>= 1) m = fmaxf(m, __shfl_down(m, off));
    if (lane == 0) red[wave] = m;
    __syncthreads();
    m = fmaxf(fmaxf(red[0], red[1]), fmaxf(red[2], red[3]));
    __syncthreads();

    float e[8];
    float sum = 0.f;
#pragma unroll
    for (int i = 0; i < 8; ++i) {
        const int s = i * 256 + t;
        e[i] = (s < len) ? expf(vals[i] - m) : 0.f;
        sum += e[i];
    }
#pragma unroll
    for (int off = 32; off > 0; off >>= 1) sum += __shfl_down(sum, off);
    if (lane == 0) red[wave] = sum;
    __syncthreads();
    const float inv = 1.f / (red[0] + red[1] + red[2] + red[3]);
#pragma unroll
    for (int i = 0; i < 8; ++i) attn[b * S + i * 256 + t] = e[i] * inv;
}

// -------- ctx partial sums over s-chunks (bf16 enc16, L3-resident) --------
__global__ __launch_bounds__(256) void ctx_partial_kernel(const short* __restrict__ enc16,
                                                          const float* __restrict__ attn,
                                                          const int* __restrict__ lens,
                                                          float* __restrict__ pc) {
    const int b = blockIdx.x >> 4, ch = blockIdx.x & 15;
    const int len = lens[b];
    const int sbase = ch * CHUNK;
    if (sbase >= len) return;
    const int ns = min(CHUNK, len - sbase);
    const int t = threadIdx.x;

    __shared__ float alds[CHUNK];
    if (t < CHUNK) alds[t] = (t < ns) ? attn[b * S + sbase + t] : 0.f;
    __syncthreads();

    const __hip_bfloat162* e2 = (const __hip_bfloat162*)(enc16 + (size_t)(b * S + sbase) * H);
    float2 acc = make_float2(0.f, 0.f);
#pragma unroll 4
    for (int s = 0; s < ns; ++s) {
        const float a = alds[s];
        const float2 e = __bfloat1622float2(e2[s * 256 + t]);
        acc.x = fmaf(a, e.x, acc.x);
        acc.y = fmaf(a, e.y, acc.y);
    }
    ((float2*)(pc + (size_t)(b * NCHUNK + ch) * H))[t] = acc;
}

// ------ out partial: 256 blocks (b x 4 quarters of the 2H cat dim) ------
__global__ __launch_bounds__(256) void out_partial_kernel(const float* __restrict__ pc,
                                                          const float* __restrict__ query,
                                                          const float* __restrict__ W_out,
                                                          const int* __restrict__ lens,
                                                          float* __restrict__ op) {
    const int b = blockIdx.x >> 2, q = blockIdx.x & 3;
    const int t = threadIdx.x;
    const int len = lens[b];
    const int nch = (len + CHUNK - 1) / CHUNK;
    __shared__ float cat[256];
    const int c0 = q * 256;
    const int ci = c0 + t;
    float val;
    if (ci < H) {
        float s = 0.f;
        for (int ch = 0; ch < nch; ++ch) s += pc[(size_t)(b * NCHUNK + ch) * H + ci];
        val = s;
    } else {
        val = query[b * H + (ci - H)];
    }
    cat[t] = val;
    __syncthreads();
    float a0 = 0.f, a1 = 0.f;
#pragma unroll 8
    for (int cc = 0; cc < 256; ++cc) {
        const float cv = cat[cc];
        a0 = fmaf(cv, W_out[(c0 + cc) * H + t], a0);
        a1 = fmaf(cv, W_out[(c0 + cc) * H + t + 256], a1);
    }
    op[(size_t)((b << 2) + q) * H + t] = a0;
    op[(size_t)((b << 2) + q) * H + t + 256] = a1;
}

// ------ out final: sum 4 partials + tanh ------
__global__ __launch_bounds__(512) void out_final_kernel(const float* __restrict__ op,
                                                        float* __restrict__ wout) {
    const int b = blockIdx.x, k = threadIdx.x;
    const size_t base = (size_t)(b << 2) * H + k;
    wout[b * H + k] = tanhf(op[base] + op[base + H] + op[base + 2 * H] + op[base + 3 * H]);
}

extern "C" void kernel_launch(void* const* d_in, const int* in_sizes, int n_in,
                              void* d_out, int out_size, void* d_ws, size_t ws_size,
                              hipStream_t stream) {
    const float* query = (const float*)d_in[0];
    const float* enc   = (const float*)d_in[1];
    const int*   lens  = (const int*)d_in[2];
    const float* W_h   = (const float*)d_in[3];
    const float* W_s   = (const float*)d_in[4];
    const float* v     = (const float*)d_in[5];
    const float* W_out = (const float*)d_in[6];

    float* out  = (float*)d_out;
    float* wout = out;          // B*H
    float* attn = out + B * H;  // B*S

    float* ws    = (float*)d_ws;
    float* qs    = ws + QS_OFF;
    float* sp    = ws + SP_OFF;
    int*   tl    = (int*)(ws + TL_OFF);
    float* pc    = ws + PC_OFF;
    short* Wt    = (short*)(ws + PC_OFF);    // aliases pc: Wt read in scores (before pc written)
    short* enc16 = (short*)(ws + E16_OFF);
    float* op    = ws + OP_OFF;

    prep_kernel<<<1601, 256, 0, stream>>>(query, W_s, W_h, enc, lens, qs, Wt, enc16, tl);
    // --- ablation probes (write nothing global; timing read from rocprof table) ---
    scores_mfma_kernel<1><<<1024, 256, 0, stream>>>(enc16, Wt, v, qs, tl, sp);  // stage only
    scores_mfma_kernel<2><<<1024, 256, 0, stream>>>(enc16, Wt, v, qs, tl, sp);  // compute only
    scores_mfma_kernel<3><<<1024, 256, 0, stream>>>(enc16, Wt, v, qs, tl, sp);  // stage+compute
    // --- real kernel ---
    scores_mfma_kernel<7><<<1024, 256, 0, stream>>>(enc16, Wt, v, qs, tl, sp);
    softmax_kernel<<<B, 256, 0, stream>>>(sp, lens, attn);
    ctx_partial_kernel<<<B * NCHUNK, 256, 0, stream>>>(enc16, attn, lens, pc);
    out_partial_kernel<<<B * 4, 256, 0, stream>>>(pc, query, W_out, lens, op);
    out_final_kernel<<<B, 512, 0, stream>>>(op, wout);
}

// Round 21
// 195.254 us; speedup vs baseline: 2.4229x; 2.4229x over previous
//
#include <hip/hip_runtime.h>
#include <hip/hip_bf16.h>
#include <math.h>

#define B 64
#define S 2048
#define H 512
#define BS (B * S)

// workspace layout (floats)
#define QS_OFF 0                           // qs: B*H
#define SP_OFF 32768                       // score partials: 8 * B*S
#define TL_OFF 1081344                     // task list ints (<=4097), reserve 16384
#define PC_OFF 1097728                     // pc: B*NCHUNK*H (Wt aliases, used before pc)
#define E16_OFF 1622016                    // enc16: B*S*H bf16
#define OP_OFF  35176448                   // out partials: 4*B*H
#define NCHUNK 16
#define CHUNK  128                         // S / NCHUNK

typedef __attribute__((ext_vector_type(8))) short short8;
typedef __attribute__((ext_vector_type(4))) short short4v;
typedef __attribute__((ext_vector_type(4))) float f32x4;

static __device__ __forceinline__ short f2bf(float f) {
    union { float f; unsigned u; } x; x.f = f;
    unsigned r = x.u + 0x7fffu + ((x.u >> 16) & 1u);   // RNE
    return (short)(r >> 16);
}

static __device__ __forceinline__ float ftanh(float x) {
    x = fminf(fmaxf(x, -30.f), 30.f);
    const float e = __builtin_amdgcn_exp2f(x * 2.8853900817779268f); // e^(2x)
    return (e - 1.f) * __builtin_amdgcn_rcpf(e + 1.f);
}

#define GLL16(g_, l_) __builtin_amdgcn_global_load_lds(                        \
    (const __attribute__((address_space(1))) void*)(g_),                      \
    (__attribute__((address_space(3))) void*)(l_), 16, 0, 0)

// ---- fused prep: [0,1024) wt_prep | [1024,1536) cvt | [1536,1600) qs | 1600 task ----
__global__ __launch_bounds__(256) void prep_kernel(const float* __restrict__ query,
                                                   const float* __restrict__ W_s,
                                                   const float* __restrict__ W_h,
                                                   const float* __restrict__ enc,
                                                   const int* __restrict__ lens,
                                                   float* __restrict__ qs,
                                                   short* __restrict__ Wt,
                                                   short* __restrict__ enc16,
                                                   int* __restrict__ tl) {
    const int bid = blockIdx.x;
    const int t = threadIdx.x;
    if (bid < 1024) {
        // Wt layout (shorts): idx = st*16384 + cg*2048 + cb*512 + l*8 + j
        // element = W_h[k][col], k = st*32 + (l>>4)*8 + j, col = cg*64 + cb*16 + (l&15)
        const int idx = bid * 256 + t;
        const int j  = idx & 7;
        const int l  = (idx >> 3) & 63;
        const int cb = (idx >> 9) & 3;
        const int cg = (idx >> 11) & 7;
        const int st = idx >> 14;
        const int k   = st * 32 + (l >> 4) * 8 + j;
        const int col = cg * 64 + cb * 16 + (l & 15);
        Wt[idx] = f2bf(W_h[k * H + col]);
    } else if (bid < 1536) {
        const int bb = bid - 1024;
        const int b = bb >> 3, seg = bb & 7;
        const int len_r = (lens[b] + 31) & ~31;
        const int start = seg * 256;
        if (start >= len_r) return;
        const int nrows = min(256, len_r - start);
        const float4* src = (const float4*)(enc + ((size_t)b * S + start) * H);
        short4v* dst = (short4v*)(enc16 + ((size_t)b * S + start) * H);
        const int nf4 = nrows * (H / 4);
        for (int u = t; u < nf4; u += 256) {
            const float4 f = src[u];
            short4v h;
            h[0] = f2bf(f.x); h[1] = f2bf(f.y); h[2] = f2bf(f.z); h[3] = f2bf(f.w);
            dst[u] = h;
        }
    } else if (bid < 1600) {
        const int b = bid - 1536;
        __shared__ float q[H];
        q[t] = query[b * H + t];
        q[t + 256] = query[b * H + t + 256];
        __syncthreads();
        float a0 = 0.f, a1 = 0.f;
#pragma unroll 8
        for (int h = 0; h < H; ++h) {
            a0 = fmaf(q[h], W_s[h * H + t], a0);
            a1 = fmaf(q[h], W_s[h * H + t + 256], a1);
        }
        qs[b * H + t] = a0;
        qs[b * H + t + 256] = a1;
    } else {
        // compacted 32-row task list: tl[0]=count; tl[1+i] = (b<<16) | tt
        if (t < 64) {
            const int b = t;
            const int cnt = (lens[b] + 31) >> 5;
            int pre = cnt;
#pragma unroll
            for (int off = 1; off < 64; off <<= 1) {
                const int up = __shfl_up(pre, off);
                if (b >= off) pre += up;
            }
            if (b == 63) tl[0] = pre;
            const int start = pre - cnt;
            for (int k = 0; k < cnt; ++k) tl[1 + start + k] = (b << 16) | k;
        }
    }
}

// ------- scores — FULL-N blocks (A amplification = 1), B streamed from L2 -------
// 512 blocks (2/CU) x 8 waves; block owns one 32-row task per rep (i = bid + rep*512),
// wave w computes cols [w*64, w*64+64). A-tile (32 rows bf16) staged ONCE into LDS
// (rows at stride 1152 + (row&7)*16 rotation -> conflict-free b128 frag reads),
// double-buffered; ONE uniform barrier per task. B-frags loaded per k-step from
// L2-resident fragment-ordered Wt (4 short8/wave/step). 4 waves/SIMD hides latency.
__global__ __launch_bounds__(512, 4) void scores_mfma_kernel(const short* __restrict__ enc16,
                                                             const short* __restrict__ Wt,
                                                             const float* __restrict__ v,
                                                             const float* __restrict__ qs,
                                                             const int* __restrict__ tl,
                                                             float* __restrict__ sp) {
    const int t = threadIdx.x;
    const int w = t >> 6, l = t & 63;
    const int g = l >> 4, c = l & 15;
    const int bid = blockIdx.x;

    __shared__ __attribute__((aligned(16))) char As[2][36864];  // 2 x 32 rows x 1152 B

    const int nt = tl[0];

    // per-lane A-frag read bases (row rotation (row&7)*16; (16+c)&7 == c&7)
    const int rot = (c & 7) << 4;
    const int abase0 = c * 1152 + rot + g * 16;
    const int abase1 = (16 + c) * 1152 + rot + g * 16;

    float vreg[4];
#pragma unroll
    for (int cb = 0; cb < 4; ++cb) vreg[cb] = v[w * 64 + cb * 16 + c];

    // wave w stages rows 4w..4w+3 of the task (1 KB contiguous each)
#define STAGE_A(buf_, b_, s_)                                                  \
    {                                                                          \
        const char* src_ = (const char*)(enc16 + ((size_t)(b_) * S + (s_) + w * 4) * H) + l * 16; \
        _Pragma("unroll")                                                      \
        for (int r_ = 0; r_ < 4; ++r_) {                                       \
            const int row_ = w * 4 + r_;                                       \
            GLL16(src_ + r_ * 1024, &As[buf_][0] + row_ * 1152 + ((row_ & 7) << 4)); \
        }                                                                      \
    }

#pragma unroll
    for (int rep = 0; rep < 8; ++rep) {
        const int i = bid + rep * 512;     // block-uniform guard
        if (i < nt) {
            const int task = tl[1 + i];
            const int b0 = task >> 16;
            const int s0 = (task & 0xffff) << 5;

            if (rep == 0) STAGE_A(0, b0, s0)
            __syncthreads();               // A(buf rep&1) ready; uniform per block

            // stage NEXT task into the other buffer (hidden under compute)
            {
                const int i2 = bid + (rep + 1) * 512;
                if (rep < 7 && i2 < nt) {
                    const int task2 = tl[1 + i2];
                    STAGE_A((rep + 1) & 1, task2 >> 16, (task2 & 0xffff) << 5)
                }
            }

            float qreg[4];
#pragma unroll
            for (int cb = 0; cb < 4; ++cb) qreg[cb] = qs[b0 * H + w * 64 + cb * 16 + c];

            const char* Ab = &As[rep & 1][0];
            const short* WtW = Wt + w * 2048 + l * 8;

            f32x4 acc[2][4];
            const f32x4 z = {0.f, 0.f, 0.f, 0.f};
#pragma unroll
            for (int rb = 0; rb < 2; ++rb)
#pragma unroll
                for (int cb = 0; cb < 4; ++cb) acc[rb][cb] = z;

#pragma unroll
            for (int st = 0; st < 16; ++st) {
                const short8 af0 = *(const short8*)(Ab + abase0 + st * 64);
                const short8 af1 = *(const short8*)(Ab + abase1 + st * 64);
                const short* bw = WtW + st * 16384;
#pragma unroll
                for (int cb = 0; cb < 4; ++cb) {
                    const short8 bf = *(const short8*)(bw + cb * 512);
                    acc[0][cb] = __builtin_amdgcn_mfma_f32_16x16x32_bf16(af0, bf, acc[0][cb], 0, 0, 0);
                    acc[1][cb] = __builtin_amdgcn_mfma_f32_16x16x32_bf16(af1, bf, acc[1][cb], 0, 0, 0);
                }
            }

            // epilogue: partial p[row] over this wave's 64 cols -> plane w
            float* spb = sp + (size_t)w * BS + (size_t)b0 * S + s0;
#pragma unroll
            for (int rb = 0; rb < 2; ++rb) {
                float pr[4] = {0.f, 0.f, 0.f, 0.f};
#pragma unroll
                for (int cb = 0; cb < 4; ++cb)
#pragma unroll
                    for (int r = 0; r < 4; ++r)
                        pr[r] += vreg[cb] * ftanh(acc[rb][cb][r] + qreg[cb]);
#pragma unroll
                for (int m = 1; m < 16; m <<= 1)
#pragma unroll
                    for (int r = 0; r < 4; ++r)
                        pr[r] += __shfl_xor(pr[r], m);
                if (c == 0) {
#pragma unroll
                    for (int r = 0; r < 4; ++r)
                        spb[rb * 16 + g * 4 + r] = pr[r];
                }
            }
        }
    }
#undef STAGE_A
}

// ------ softmax over S (sums 8 col-group partials), write attn ------
__global__ __launch_bounds__(256) void softmax_kernel(const float* __restrict__ sp,
                                                      const int* __restrict__ lens,
                                                      float* __restrict__ attn) {
    const int b = blockIdx.x, t = threadIdx.x;
    const int len = lens[b];
    const int wave = t >> 6, lane = t & 63;
    __shared__ float red[4];

    float vals[8];
    float m = -INFINITY;
#pragma unroll
    for (int i = 0; i < 8; ++i) {
        const int s = i * 256 + t;
        if (s < len) {
            const size_t o = (size_t)b * S + s;
            float acc = 0.f;
#pragma unroll
            for (int p = 0; p < 8; ++p) acc += sp[(size_t)p * BS + o];
            vals[i] = acc;
        } else vals[i] = -INFINITY;
        m = fmaxf(m, vals[i]);
    }
#pragma unroll
    for (int off = 32; off > 0; off >>= 1) m = fmaxf(m, __shfl_down(m, off));
    if (lane == 0) red[wave] = m;
    __syncthreads();
    m = fmaxf(fmaxf(red[0], red[1]), fmaxf(red[2], red[3]));
    __syncthreads();

    float e[8];
    float sum = 0.f;
#pragma unroll
    for (int i = 0; i < 8; ++i) {
        const int s = i * 256 + t;
        e[i] = (s < len) ? expf(vals[i] - m) : 0.f;
        sum += e[i];
    }
#pragma unroll
    for (int off = 32; off > 0; off >>= 1) sum += __shfl_down(sum, off);
    if (lane == 0) red[wave] = sum;
    __syncthreads();
    const float inv = 1.f / (red[0] + red[1] + red[2] + red[3]);
#pragma unroll
    for (int i = 0; i < 8; ++i) attn[b * S + i * 256 + t] = e[i] * inv;
}

// -------- ctx partial sums over s-chunks (bf16 enc16, L3-resident) --------
__global__ __launch_bounds__(256) void ctx_partial_kernel(const short* __restrict__ enc16,
                                                          const float* __restrict__ attn,
                                                          const int* __restrict__ lens,
                                                          float* __restrict__ pc) {
    const int b = blockIdx.x >> 4, ch = blockIdx.x & 15;
    const int len = lens[b];
    const int sbase = ch * CHUNK;
    if (sbase >= len) return;
    const int ns = min(CHUNK, len - sbase);
    const int t = threadIdx.x;

    __shared__ float alds[CHUNK];
    if (t < CHUNK) alds[t] = (t < ns) ? attn[b * S + sbase + t] : 0.f;
    __syncthreads();

    const __hip_bfloat162* e2 = (const __hip_bfloat162*)(enc16 + (size_t)(b * S + sbase) * H);
    float2 acc = make_float2(0.f, 0.f);
#pragma unroll 4
    for (int s = 0; s < ns; ++s) {
        const float a = alds[s];
        const float2 e = __bfloat1622float2(e2[s * 256 + t]);
        acc.x = fmaf(a, e.x, acc.x);
        acc.y = fmaf(a, e.y, acc.y);
    }
    ((float2*)(pc + (size_t)(b * NCHUNK + ch) * H))[t] = acc;
}

// ------ out partial: 256 blocks (b x 4 quarters of the 2H cat dim) ------
__global__ __launch_bounds__(256) void out_partial_kernel(const float* __restrict__ pc,
                                                          const float* __restrict__ query,
                                                          const float* __restrict__ W_out,
                                                          const int* __restrict__ lens,
                                                          float* __restrict__ op) {
    const int b = blockIdx.x >> 2, q = blockIdx.x & 3;
    const int t = threadIdx.x;
    const int len = lens[b];
    const int nch = (len + CHUNK - 1) / CHUNK;
    __shared__ float cat[256];
    const int c0 = q * 256;
    const int ci = c0 + t;
    float val;
    if (ci < H) {
        float s = 0.f;
        for (int ch = 0; ch < nch; ++ch) s += pc[(size_t)(b * NCHUNK + ch) * H + ci];
        val = s;
    } else {
        val = query[b * H + (ci - H)];
    }
    cat[t] = val;
    __syncthreads();
    float a0 = 0.f, a1 = 0.f;
#pragma unroll 8
    for (int cc = 0; cc < 256; ++cc) {
        const float cv = cat[cc];
        a0 = fmaf(cv, W_out[(c0 + cc) * H + t], a0);
        a1 = fmaf(cv, W_out[(c0 + cc) * H + t + 256], a1);
    }
    op[(size_t)((b << 2) + q) * H + t] = a0;
    op[(size_t)((b << 2) + q) * H + t + 256] = a1;
}

// ------ out final: sum 4 partials + tanh ------
__global__ __launch_bounds__(512) void out_final_kernel(const float* __restrict__ op,
                                                        float* __restrict__ wout) {
    const int b = blockIdx.x, k = threadIdx.x;
    const size_t base = (size_t)(b << 2) * H + k;
    wout[b * H + k] = tanhf(op[base] + op[base + H] + op[base + 2 * H] + op[base + 3 * H]);
}

extern "C" void kernel_launch(void* const* d_in, const int* in_sizes, int n_in,
                              void* d_out, int out_size, void* d_ws, size_t ws_size,
                              hipStream_t stream) {
    const float* query = (const float*)d_in[0];
    const float* enc   = (const float*)d_in[1];
    const int*   lens  = (const int*)d_in[2];
    const float* W_h   = (const float*)d_in[3];
    const float* W_s   = (const float*)d_in[4];
    const float* v     = (const float*)d_in[5];
    const float* W_out = (const float*)d_in[6];

    float* out  = (float*)d_out;
    float* wout = out;          // B*H
    float* attn = out + B * H;  // B*S

    float* ws    = (float*)d_ws;
    float* qs    = ws + QS_OFF;
    float* sp    = ws + SP_OFF;
    int*   tl    = (int*)(ws + TL_OFF);
    float* pc    = ws + PC_OFF;
    short* Wt    = (short*)(ws + PC_OFF);    // aliases pc: Wt read in scores (before pc written)
    short* enc16 = (short*)(ws + E16_OFF);
    float* op    = ws + OP_OFF;

    prep_kernel<<<1601, 256, 0, stream>>>(query, W_s, W_h, enc, lens, qs, Wt, enc16, tl);
    scores_mfma_kernel<<<512, 512, 0, stream>>>(enc16, Wt, v, qs, tl, sp);
    softmax_kernel<<<B, 256, 0, stream>>>(sp, lens, attn);
    ctx_partial_kernel<<<B * NCHUNK, 256, 0, stream>>>(enc16, attn, lens, pc);
    out_partial_kernel<<<B * 4, 256, 0, stream>>>(pc, query, W_out, lens, op);
    out_final_kernel<<<B, 512, 0, stream>>>(op, wout);
}

// Round 22
// 151.688 us; speedup vs baseline: 3.1188x; 1.2872x over previous
//
#include <hip/hip_runtime.h>
#include <hip/hip_bf16.h>
#include <math.h>

#define B 64
#define S 2048
#define H 512
#define BS (B * S)

// workspace layout (floats)
#define QS_OFF 0                           // qs: B*H
#define SP_OFF 32768                       // score partials: 8 * B*S
#define TL_OFF 1081344                     // task list ints (<=2049), reserve 16384
#define PC_OFF 1097728                     // pc: B*NCHUNK*H (Wt aliases, used before pc)
#define OP_OFF 1622016                     // out partials: 4*B*H
#define NCHUNK 16
#define CHUNK  128                         // S / NCHUNK

typedef __attribute__((ext_vector_type(8))) short short8;
typedef __attribute__((ext_vector_type(4))) float f32x4;

static __device__ __forceinline__ short f2bf(float f) {
    union { float f; unsigned u; } x; x.f = f;
    unsigned r = x.u + 0x7fffu + ((x.u >> 16) & 1u);   // RNE
    return (short)(r >> 16);
}

static __device__ __forceinline__ float ftanh(float x) {
    x = fminf(fmaxf(x, -30.f), 30.f);
    const float e = __builtin_amdgcn_exp2f(x * 2.8853900817779268f); // e^(2x)
    return (e - 1.f) * __builtin_amdgcn_rcpf(e + 1.f);
}

static __device__ __forceinline__ short8 cvt8(float4 a, float4 b) {
    union { short8 s; __hip_bfloat162 h[4]; } u;
    u.h[0] = __float22bfloat162_rn(make_float2(a.x, a.y));
    u.h[1] = __float22bfloat162_rn(make_float2(a.z, a.w));
    u.h[2] = __float22bfloat162_rn(make_float2(b.x, b.y));
    u.h[3] = __float22bfloat162_rn(make_float2(b.z, b.w));
    return u.s;
}

// ---- fused prep: [0,1024) wt_prep | [1024,1088) qs | 1088 task ----
__global__ __launch_bounds__(256) void prep_kernel(const float* __restrict__ query,
                                                   const float* __restrict__ W_s,
                                                   const float* __restrict__ W_h,
                                                   const int* __restrict__ lens,
                                                   float* __restrict__ qs,
                                                   short* __restrict__ Wt,
                                                   int* __restrict__ tl) {
    const int bid = blockIdx.x;
    const int t = threadIdx.x;
    if (bid < 1024) {
        // Wt layout (shorts): idx = st*16384 + cg*2048 + cb*512 + l*8 + j
        // element = W_h[k][col], k = st*32 + (l>>4)*8 + j, col = cg*64 + cb*16 + (l&15)
        const int idx = bid * 256 + t;
        const int j  = idx & 7;
        const int l  = (idx >> 3) & 63;
        const int cb = (idx >> 9) & 3;
        const int cg = (idx >> 11) & 7;
        const int st = idx >> 14;
        const int k   = st * 32 + (l >> 4) * 8 + j;
        const int col = cg * 64 + cb * 16 + (l & 15);
        Wt[idx] = f2bf(W_h[k * H + col]);
    } else if (bid < 1088) {
        const int b = bid - 1024;
        __shared__ float q[H];
        q[t] = query[b * H + t];
        q[t + 256] = query[b * H + t + 256];
        __syncthreads();
        float a0 = 0.f, a1 = 0.f;
#pragma unroll 8
        for (int h = 0; h < H; ++h) {
            a0 = fmaf(q[h], W_s[h * H + t], a0);
            a1 = fmaf(q[h], W_s[h * H + t + 256], a1);
        }
        qs[b * H + t] = a0;
        qs[b * H + t + 256] = a1;
    } else {
        // compacted 32-row task list: tl[0]=count; tl[1+i] = (b<<16) | tt
        if (t < 64) {
            const int b = t;
            const int cnt = (lens[b] + 31) >> 5;
            int pre = cnt;
#pragma unroll
            for (int off = 1; off < 64; off <<= 1) {
                const int up = __shfl_up(pre, off);
                if (b >= off) pre += up;
            }
            if (b == 63) tl[0] = pre;
            const int start = pre - cnt;
            for (int k = 0; k < cnt; ++k) tl[1 + start + k] = (b << 16) | k;
        }
    }
}

// ------- scores — FULL-N blocks (A amplification = 1), fp32 A reg-staged, B from L2 -------
// 512 blocks (2/CU) x 8 waves; block owns one 32-row task per rep (i = bid + rep*512),
// wave w computes cols [w*64, w*64+64). A: wave stages its 4 fp32 rows -> regs -> cvt ->
// bf16 LDS rows (stride 1152 + (row&7)*16 rotation, conflict-free b128 reads), double-
// buffered, T14 split (loads before compute, ds_write after). ONE barrier per task.
// B: depth-2 explicit register ring from L2-resident fragment-ordered Wt.
__global__ __launch_bounds__(512, 4) void scores_mfma_kernel(const float* __restrict__ enc,
                                                             const short* __restrict__ Wt,
                                                             const float* __restrict__ v,
                                                             const float* __restrict__ qs,
                                                             const int* __restrict__ tl,
                                                             float* __restrict__ sp) {
    const int t = threadIdx.x;
    const int w = t >> 6, l = t & 63;
    const int g = l >> 4, c = l & 15;
    const int bid = blockIdx.x;

    __shared__ __attribute__((aligned(16))) char As[2][36864];  // 2 x 32 rows x 1152 B

    const int nt = tl[0];

    // per-lane A-frag read bases (row rotation (row&7)*16; (16+c)&7 == c&7)
    const int rot = (c & 7) << 4;
    const int abase0 = c * 1152 + rot + g * 16;
    const int abase1 = (16 + c) * 1152 + rot + g * 16;

    float vreg[4];
#pragma unroll
    for (int cb = 0; cb < 4; ++cb) vreg[cb] = v[w * 64 + cb * 16 + c];

    // wave w stages rows 4w..4w+3; lane l covers floats [l*8, l*8+8) of each row
#define LOADA(AFv, b_, s_)                                                     \
    _Pragma("unroll")                                                          \
    for (int r_ = 0; r_ < 4; ++r_) {                                           \
        const float* p_ = enc + ((size_t)(b_) * S + (s_) + w * 4 + r_) * H + l * 8; \
        AFv[r_][0] = *(const float4*)(p_);                                     \
        AFv[r_][1] = *(const float4*)(p_ + 4);                                 \
    }

#define WRITEA(AFv, buf_)                                                      \
    _Pragma("unroll")                                                          \
    for (int r_ = 0; r_ < 4; ++r_) {                                           \
        const int row_ = w * 4 + r_;                                           \
        *(short8*)(&As[buf_][0] + row_ * 1152 + ((row_ & 7) << 4) + l * 16) =  \
            cvt8(AFv[r_][0], AFv[r_][1]);                                      \
    }

#define LOADB(buf_, st_)                                                       \
    _Pragma("unroll")                                                          \
    for (int cb = 0; cb < 4; ++cb)                                             \
        buf_[cb] = *(const short8*)(WtW + (st_) * 16384 + cb * 512);

#define DOMFMA(bf_, st_)                                                       \
    {                                                                          \
        const short8 af0 = *(const short8*)(Ab + abase0 + (st_) * 64);         \
        const short8 af1 = *(const short8*)(Ab + abase1 + (st_) * 64);         \
        _Pragma("unroll")                                                      \
        for (int cb = 0; cb < 4; ++cb) {                                       \
            acc[0][cb] = __builtin_amdgcn_mfma_f32_16x16x32_bf16(af0, bf_[cb], acc[0][cb], 0, 0, 0); \
            acc[1][cb] = __builtin_amdgcn_mfma_f32_16x16x32_bf16(af1, bf_[cb], acc[1][cb], 0, 0, 0); \
        }                                                                      \
    }

    // prologue: stage task(bid) into buf0
    {
        const int i = bid;
        if (i < nt) {
            const int task = tl[1 + i];
            float4 AF[4][2];
            LOADA(AF, task >> 16, (task & 0xffff) << 5)
            WRITEA(AF, 0)
        }
    }

#pragma unroll
    for (int rep = 0; rep < 8; ++rep) {
        const int i = bid + rep * 512;     // block-uniform guard
        if (i < nt) {
            __syncthreads();               // buf(rep&1) ready (writes from prev rep/prologue)

            const int task = tl[1 + i];
            const int b0 = task >> 16;
            const int s0 = (task & 0xffff) << 5;

            // issue NEXT task's global loads early (T14) — hidden under compute
            float4 AF[4][2];
            const int i2 = i + 512;
            const bool havenext = (rep < 7) && (i2 < nt);
            if (havenext) {
                const int task2 = tl[1 + i2];
                LOADA(AF, task2 >> 16, (task2 & 0xffff) << 5)
            }

            float qreg[4];
#pragma unroll
            for (int cb = 0; cb < 4; ++cb) qreg[cb] = qs[b0 * H + w * 64 + cb * 16 + c];

            const char* Ab = &As[rep & 1][0];
            const short* WtW = Wt + w * 2048 + l * 8;

            f32x4 acc[2][4];
            const f32x4 z = {0.f, 0.f, 0.f, 0.f};
#pragma unroll
            for (int rb = 0; rb < 2; ++rb)
#pragma unroll
                for (int cb = 0; cb < 4; ++cb) acc[rb][cb] = z;

            // 16 k-steps, depth-2 B register ring (named bufs, static idx)
            short8 bA[4], bB[4];
            LOADB(bA, 0)
#pragma unroll
            for (int st = 0; st < 16; st += 2) {
                LOADB(bB, st + 1)
                DOMFMA(bA, st)
                if (st + 2 < 16) LOADB(bA, st + 2)
                DOMFMA(bB, st + 1)
            }

            // write next task's A into the other buffer (visible after next barrier)
            if (havenext) WRITEA(AF, (rep + 1) & 1)

            // epilogue: partial p[row] over this wave's 64 cols -> plane w
            float* spb = sp + (size_t)w * BS + (size_t)b0 * S + s0;
#pragma unroll
            for (int rb = 0; rb < 2; ++rb) {
                float pr[4] = {0.f, 0.f, 0.f, 0.f};
#pragma unroll
                for (int cb = 0; cb < 4; ++cb)
#pragma unroll
                    for (int r = 0; r < 4; ++r)
                        pr[r] += vreg[cb] * ftanh(acc[rb][cb][r] + qreg[cb]);
#pragma unroll
                for (int m = 1; m < 16; m <<= 1)
#pragma unroll
                    for (int r = 0; r < 4; ++r)
                        pr[r] += __shfl_xor(pr[r], m);
                if (c == 0) {
#pragma unroll
                    for (int r = 0; r < 4; ++r)
                        spb[rb * 16 + g * 4 + r] = pr[r];
                }
            }
        }
    }
#undef LOADA
#undef WRITEA
#undef LOADB
#undef DOMFMA
}

// ------ softmax over S (sums 8 col-group partials), write attn ------
__global__ __launch_bounds__(256) void softmax_kernel(const float* __restrict__ sp,
                                                      const int* __restrict__ lens,
                                                      float* __restrict__ attn) {
    const int b = blockIdx.x, t = threadIdx.x;
    const int len = lens[b];
    const int wave = t >> 6, lane = t & 63;
    __shared__ float red[4];

    float vals[8];
    float m = -INFINITY;
#pragma unroll
    for (int i = 0; i < 8; ++i) {
        const int s = i * 256 + t;
        if (s < len) {
            const size_t o = (size_t)b * S + s;
            float acc = 0.f;
#pragma unroll
            for (int p = 0; p < 8; ++p) acc += sp[(size_t)p * BS + o];
            vals[i] = acc;
        } else vals[i] = -INFINITY;
        m = fmaxf(m, vals[i]);
    }
#pragma unroll
    for (int off = 32; off > 0; off >>= 1) m = fmaxf(m, __shfl_down(m, off));
    if (lane == 0) red[wave] = m;
    __syncthreads();
    m = fmaxf(fmaxf(red[0], red[1]), fmaxf(red[2], red[3]));
    __syncthreads();

    float e[8];
    float sum = 0.f;
#pragma unroll
    for (int i = 0; i < 8; ++i) {
        const int s = i * 256 + t;
        e[i] = (s < len) ? expf(vals[i] - m) : 0.f;
        sum += e[i];
    }
#pragma unroll
    for (int off = 32; off > 0; off >>= 1) sum += __shfl_down(sum, off);
    if (lane == 0) red[wave] = sum;
    __syncthreads();
    const float inv = 1.f / (red[0] + red[1] + red[2] + red[3]);
#pragma unroll
    for (int i = 0; i < 8; ++i) attn[b * S + i * 256 + t] = e[i] * inv;
}

// -------- ctx partial sums over s-chunks (fp32 enc) --------
__global__ __launch_bounds__(256) void ctx_partial_kernel(const float* __restrict__ enc,
                                                          const float* __restrict__ attn,
                                                          const int* __restrict__ lens,
                                                          float* __restrict__ pc) {
    const int b = blockIdx.x >> 4, ch = blockIdx.x & 15;
    const int len = lens[b];
    const int sbase = ch * CHUNK;
    if (sbase >= len) return;
    const int ns = min(CHUNK, len - sbase);
    const int t = threadIdx.x;

    __shared__ float alds[CHUNK];
    if (t < CHUNK) alds[t] = (t < ns) ? attn[b * S + sbase + t] : 0.f;
    __syncthreads();

    const float2* e2 = (const float2*)(enc + (size_t)(b * S + sbase) * H);
    float2 acc = make_float2(0.f, 0.f);
#pragma unroll 4
    for (int s = 0; s < ns; ++s) {
        const float a = alds[s];
        const float2 e = e2[s * 256 + t];
        acc.x = fmaf(a, e.x, acc.x);
        acc.y = fmaf(a, e.y, acc.y);
    }
    ((float2*)(pc + (size_t)(b * NCHUNK + ch) * H))[t] = acc;
}

// ------ out partial: 256 blocks (b x 4 quarters of the 2H cat dim) ------
__global__ __launch_bounds__(256) void out_partial_kernel(const float* __restrict__ pc,
                                                          const float* __restrict__ query,
                                                          const float* __restrict__ W_out,
                                                          const int* __restrict__ lens,
                                                          float* __restrict__ op) {
    const int b = blockIdx.x >> 2, q = blockIdx.x & 3;
    const int t = threadIdx.x;
    const int len = lens[b];
    const int nch = (len + CHUNK - 1) / CHUNK;
    __shared__ float cat[256];
    const int c0 = q * 256;
    const int ci = c0 + t;
    float val;
    if (ci < H) {
        float s = 0.f;
        for (int ch = 0; ch < nch; ++ch) s += pc[(size_t)(b * NCHUNK + ch) * H + ci];
        val = s;
    } else {
        val = query[b * H + (ci - H)];
    }
    cat[t] = val;
    __syncthreads();
    float a0 = 0.f, a1 = 0.f;
#pragma unroll 8
    for (int cc = 0; cc < 256; ++cc) {
        const float cv = cat[cc];
        a0 = fmaf(cv, W_out[(c0 + cc) * H + t], a0);
        a1 = fmaf(cv, W_out[(c0 + cc) * H + t + 256], a1);
    }
    op[(size_t)((b << 2) + q) * H + t] = a0;
    op[(size_t)((b << 2) + q) * H + t + 256] = a1;
}

// ------ out final: sum 4 partials + tanh ------
__global__ __launch_bounds__(512) void out_final_kernel(const float* __restrict__ op,
                                                        float* __restrict__ wout) {
    const int b = blockIdx.x, k = threadIdx.x;
    const size_t base = (size_t)(b << 2) * H + k;
    wout[b * H + k] = tanhf(op[base] + op[base + H] + op[base + 2 * H] + op[base + 3 * H]);
}

extern "C" void kernel_launch(void* const* d_in, const int* in_sizes, int n_in,
                              void* d_out, int out_size, void* d_ws, size_t ws_size,
                              hipStream_t stream) {
    const float* query = (const float*)d_in[0];
    const float* enc   = (const float*)d_in[1];
    const int*   lens  = (const int*)d_in[2];
    const float* W_h   = (const float*)d_in[3];
    const float* W_s   = (const float*)d_in[4];
    const float* v     = (const float*)d_in[5];
    const float* W_out = (const float*)d_in[6];

    float* out  = (float*)d_out;
    float* wout = out;          // B*H
    float* attn = out + B * H;  // B*S

    float* ws = (float*)d_ws;
    float* qs = ws + QS_OFF;
    float* sp = ws + SP_OFF;
    int*   tl = (int*)(ws + TL_OFF);
    float* pc = ws + PC_OFF;
    short* Wt = (short*)(ws + PC_OFF);   // aliases pc: Wt read in scores (before pc written)
    float* op = ws + OP_OFF;

    prep_kernel<<<1089, 256, 0, stream>>>(query, W_s, W_h, lens, qs, Wt, tl);
    scores_mfma_kernel<<<512, 512, 0, stream>>>(enc, Wt, v, qs, tl, sp);
    softmax_kernel<<<B, 256, 0, stream>>>(sp, lens, attn);
    ctx_partial_kernel<<<B * NCHUNK, 256, 0, stream>>>(enc, attn, lens, pc);
    out_partial_kernel<<<B * 4, 256, 0, stream>>>(pc, query, W_out, lens, op);
    out_final_kernel<<<B, 512, 0, stream>>>(op, wout);
}